// Round 16
// baseline (465.166 us; speedup 1.0000x reference)
//
#include <hip/hip_runtime.h>

#define N_NODES  100000
#define N_EDGES  1600000
#define DIM      64
#define N_GRAPHS 128
#define OUT_DIM  10
#define SCAN_NB    196
#define SCAN_CHUNK 512      // 196*512 = 100352 >= N_NODES
#define RANGE_BITS 14
#define RANGE_SIZE 16384    // nodes per dst-range
#define N_RANGES   7        // 7*16384 = 114688 >= N_NODES
#define NODE_PAD   (N_RANGES * RANGE_SIZE) // 114688
#define P_CHUNKS   512
#define P_EDGES    (N_EDGES / P_CHUNKS)    // 3125
#define SUB        16       // subchunks per range for histoR/fillR

typedef unsigned int uint;
typedef unsigned short ushort;
typedef __attribute__((ext_vector_type(8))) short short8;   // 8 bf16 = 4 VGPRs
typedef __attribute__((ext_vector_type(4))) float f32x4;

__device__ __forceinline__ uint f2bf(float x) {   // fp32 -> bf16 bits (RNE)
    uint b = __float_as_uint(x);
    b += 0x7fffu + ((b >> 16) & 1u);
    return b >> 16;
}

// ================= CSR build: range-partition first, then per-range CSR =========

__global__ void count224_kernel(const int* __restrict__ dst, int* __restrict__ counts224) {
    __shared__ int cnt[8];
    const int c = blockIdx.x, tid = threadIdx.x;
    if (tid < 8) cnt[tid] = 0;
    __syncthreads();
    int c0 = 0, c1 = 0, c2 = 0, c3 = 0, c4 = 0, c5 = 0, c6 = 0;
    const int beg = c * P_EDGES, end = beg + P_EDGES;
    for (int i = beg + tid; i < end; i += 256) {
        int r = dst[i] >> RANGE_BITS;
        c0 += (r == 0); c1 += (r == 1); c2 += (r == 2); c3 += (r == 3);
        c4 += (r == 4); c5 += (r == 5); c6 += (r == 6);
    }
    atomicAdd(&cnt[0], c0); atomicAdd(&cnt[1], c1); atomicAdd(&cnt[2], c2);
    atomicAdd(&cnt[3], c3); atomicAdd(&cnt[4], c4); atomicAdd(&cnt[5], c5);
    atomicAdd(&cnt[6], c6);
    __syncthreads();
    if (tid < N_RANGES) counts224[tid * P_CHUNKS + c] = cnt[tid];   // r-major
}

__global__ void scan224_kernel(const int* __restrict__ counts224, int* __restrict__ regionOff,
                               int* __restrict__ rangeStart) {
    __shared__ int sc[1024];
    const int t = threadIdx.x;
    const int NE = N_RANGES * P_CHUNKS;   // 3584 = 896*4
    int v[4];
    int s = 0;
#pragma unroll
    for (int k = 0; k < 4; ++k) {
        const int idx = t * 4 + k;
        v[k] = (idx < NE) ? counts224[idx] : 0;
        s += v[k];
    }
    sc[t] = s;
    __syncthreads();
    for (int off = 1; off < 1024; off <<= 1) {
        int u = (t >= off) ? sc[t - off] : 0;
        __syncthreads();
        sc[t] += u;
        __syncthreads();
    }
    int base = sc[t] - s;   // exclusive prefix for idx = t*4
#pragma unroll
    for (int k = 0; k < 4; ++k) {
        const int idx = t * 4 + k;
        if (idx < NE) {
            regionOff[idx] = base;
            if ((idx & (P_CHUNKS - 1)) == 0) rangeStart[idx >> 9] = base;
            base += v[k];
        }
    }
    if (t == 1023) rangeStart[N_RANGES] = sc[1023];   // total = N_EDGES
}

__global__ __launch_bounds__(256) void partition_kernel(
    const int* __restrict__ src, const int* __restrict__ dst,
    const int* __restrict__ regionOff, uint2* __restrict__ epart) {
    __shared__ int pos[8];
    const int c = blockIdx.x, tid = threadIdx.x;
    if (tid < N_RANGES) pos[tid] = regionOff[tid * P_CHUNKS + c];
    __syncthreads();
    const int beg = c * P_EDGES, end = beg + P_EDGES;
    for (int i = beg + tid; i < end; i += 256) {
        int d = dst[i], s = src[i];
        int p = atomicAdd(&pos[d >> RANGE_BITS], 1);
        epart[p] = make_uint2((uint)s, (uint)d);
    }
}

__global__ __launch_bounds__(1024) void histoR_kernel(const uint2* __restrict__ epart,
                                                      const int* __restrict__ rangeStart,
                                                      int* __restrict__ countsS) {
    __shared__ int h[RANGE_SIZE];
    const int r = blockIdx.x & 7;           // XCD = r
    if (r >= N_RANGES) return;
    const int s = blockIdx.x >> 3;
    const int tid = threadIdx.x;
    for (int j = tid; j < RANGE_SIZE; j += 1024) h[j] = 0;
    __syncthreads();
    const int e0 = rangeStart[r], e1 = rangeStart[r + 1];
    const int len = e1 - e0;
    const int a = e0 + (int)((long long)len * s / SUB);
    const int b = e0 + (int)((long long)len * (s + 1) / SUB);
    for (int i = a + tid; i < b; i += 1024)
        atomicAdd(&h[epart[i].y & (RANGE_SIZE - 1)], 1);
    __syncthreads();
    int* outp = countsS + (s * N_RANGES + r) * RANGE_SIZE;
    for (int j = tid; j < RANGE_SIZE; j += 1024) outp[j] = h[j];
}

__global__ void scanA_kernel(const int* __restrict__ countsS, int* __restrict__ blockSums, int n) {
    __shared__ int red[256];
    const int b = blockIdx.x, t = threadIdx.x;
    int sum = 0;
#pragma unroll
    for (int k = 0; k < 2; ++k) {
        const int node = b * SCAN_CHUNK + t * 2 + k;
        if (node < n) {
            const int r = node >> RANGE_BITS, jj = node & (RANGE_SIZE - 1);
            for (int s = 0; s < SUB; ++s)
                sum += countsS[(s * N_RANGES + r) * RANGE_SIZE + jj];
        }
    }
    red[t] = sum;
    __syncthreads();
    for (int off = 128; off > 0; off >>= 1) {
        if (t < off) red[t] += red[t + off];
        __syncthreads();
    }
    if (t == 0) blockSums[b] = red[0];
}

__global__ void scanB_kernel(const int* __restrict__ blockSums, int* __restrict__ blockOffs,
                             int* __restrict__ row_ptr) {
    __shared__ int sc[256];
    const int t = threadIdx.x;
    const int v = (t < SCAN_NB) ? blockSums[t] : 0;
    sc[t] = v;
    __syncthreads();
    for (int off = 1; off < 256; off <<= 1) {
        int u = (t >= off) ? sc[t - off] : 0;
        __syncthreads();
        sc[t] += u;
        __syncthreads();
    }
    if (t < SCAN_NB) blockOffs[t] = sc[t] - v;   // exclusive block offset
    if (t == 255) row_ptr[N_NODES] = sc[255];    // total == N_EDGES
}

__global__ void scanC_kernel(const int* __restrict__ countsS, const int* __restrict__ blockOffs,
                             int* __restrict__ row_ptr, int* __restrict__ baseS, int n) {
    __shared__ int sc[256];
    const int b = blockIdx.x, t = threadIdx.x;
    const int node0 = b * SCAN_CHUNK + t * 2;
    int cnt0[SUB], cnt1[SUB];
    int tot0 = 0, tot1 = 0;
    if (node0 < n) {
        const int r = node0 >> RANGE_BITS, jj = node0 & (RANGE_SIZE - 1);
        for (int s = 0; s < SUB; ++s) {
            cnt0[s] = countsS[(s * N_RANGES + r) * RANGE_SIZE + jj];
            tot0 += cnt0[s];
        }
    }
    if (node0 + 1 < n) {
        const int r = (node0 + 1) >> RANGE_BITS, jj = (node0 + 1) & (RANGE_SIZE - 1);
        for (int s = 0; s < SUB; ++s) {
            cnt1[s] = countsS[(s * N_RANGES + r) * RANGE_SIZE + jj];
            tot1 += cnt1[s];
        }
    }
    const int ssum = tot0 + tot1;
    sc[t] = ssum;
    __syncthreads();
    for (int off = 1; off < 256; off <<= 1) {
        int u = (t >= off) ? sc[t - off] : 0;
        __syncthreads();
        sc[t] += u;
        __syncthreads();
    }
    const int pre = blockOffs[b] + sc[t] - ssum;
    if (node0 < n) {
        row_ptr[node0] = pre;
        int run = pre;
        for (int s = 0; s < SUB; ++s) { baseS[s * NODE_PAD + node0] = run; run += cnt0[s]; }
    }
    if (node0 + 1 < n) {
        const int pre1 = pre + tot0;
        row_ptr[node0 + 1] = pre1;
        int run = pre1;
        for (int s = 0; s < SUB; ++s) { baseS[s * NODE_PAD + node0 + 1] = run; run += cnt1[s]; }
    }
}

__global__ __launch_bounds__(1024) void fillR_kernel(const uint2* __restrict__ epart,
                                                     const int* __restrict__ rangeStart,
                                                     const int* __restrict__ baseS,
                                                     int* __restrict__ col_idx) {
    __shared__ int slots[RANGE_SIZE];
    const int r = blockIdx.x & 7;           // XCD = r
    if (r >= N_RANGES) return;
    const int s = blockIdx.x >> 3;
    const int tid = threadIdx.x;
    const int* bp = baseS + s * NODE_PAD + r * RANGE_SIZE;
    for (int j = tid; j < RANGE_SIZE; j += 1024) slots[j] = bp[j];
    __syncthreads();
    const int e0 = rangeStart[r], e1 = rangeStart[r + 1];
    const int len = e1 - e0;
    const int a = e0 + (int)((long long)len * s / SUB);
    const int b = e0 + (int)((long long)len * (s + 1) / SUB);
    for (int i = a + tid; i < b; i += 1024) {
        uint2 e = epart[i];
        int pos = atomicAdd(&slots[e.y & (RANGE_SIZE - 1)], 1);
        col_idx[pos] = (int)e.x;
    }
}

// ---------------- x (fp32) -> bf16 rows ----------------

__global__ void cvt_kernel(const float* __restrict__ x, ushort* __restrict__ xb, int n4) {
    int idx = blockIdx.x * blockDim.x + threadIdx.x;
    if (idx >= n4) return;
    float4 v = ((const float4*)x)[idx];
    uint2 o;
    o.x = f2bf(v.x) | (f2bf(v.y) << 16);
    o.y = f2bf(v.z) | (f2bf(v.w) << 16);
    ((uint2*)xb)[idx] = o;
}

// ---------------- Weight repack: MFMA fragment layouts, once per launch ----------

__global__ void repack_kernel(const float* __restrict__ W1, const float* __restrict__ W2,
                              uint4* __restrict__ Wp) {
    const int wave = (blockIdx.x * blockDim.x + threadIdx.x) >> 6;
    if (wave >= 10) return;
    const int layer = wave >> 1;
    const float* W = (wave & 1) ? (W2 + layer * 4096) : (W1 + layer * 4096);
    const int lane = threadIdx.x & 63;
    const int n15 = lane & 15, quad = lane >> 4;
#pragma unroll
    for (int f = 0; f < 8; ++f) {
        const int outer = f >> 1, h = f & 1;
        uint p[4];
#pragma unroll
        for (int pj = 0; pj < 4; ++pj) {
            const int k0 = h * 32 + quad * 8 + 2 * pj;
            uint lo = f2bf(W[k0 * 64 + outer * 16 + n15]);
            uint hi = f2bf(W[(k0 + 1) * 64 + outer * 16 + n15]);
            p[pj] = lo | (hi << 16);
        }
        Wp[(wave * 8 + f) * 64 + lane] = make_uint4(p[0], p[1], p[2], p[3]);
    }
}

// ======== FUSED GIN layer: agg (gather) + MFMA MLP, one wave per 16-node tile ====
// R15 lesson: 512 blocks = 2 blocks/CU left half the VGPR-permitted occupancy
// idle (15% occ). Grid = ntiles/4 -> ~4 resident blocks/CU (4 waves/SIMD cap),
// one tile per wave.

__device__ __forceinline__ void add_unpack(float acc[8], uint4 v) {
    acc[0] += __uint_as_float(v.x << 16);
    acc[1] += __uint_as_float(v.x & 0xffff0000u);
    acc[2] += __uint_as_float(v.y << 16);
    acc[3] += __uint_as_float(v.y & 0xffff0000u);
    acc[4] += __uint_as_float(v.z << 16);
    acc[5] += __uint_as_float(v.z & 0xffff0000u);
    acc[6] += __uint_as_float(v.w << 16);
    acc[7] += __uint_as_float(v.w & 0xffff0000u);
}

__global__ __launch_bounds__(256) void gin_fused_kernel(
    const ushort* __restrict__ hin, ushort* __restrict__ hout,
    const int* __restrict__ row_ptr, const int* __restrict__ col_idx,
    const uint4* __restrict__ Wp,   // layer frags: [0..7]=W1^T, [8..15]=W2
    const float* __restrict__ b1, const float* __restrict__ gamma,
    const float* __restrict__ beta, const float* __restrict__ rmean,
    const float* __restrict__ rvar, const float* __restrict__ b2, int ntiles)
{
    __shared__ __align__(16) ushort T[4][16][72];   // t rows (stride 72: 16B-aligned rows)
    __shared__ __align__(16) ushort U[4][16][72];   // relu(BN(t@W1+b1)) rows
    const uint4* __restrict__ hb4 = (const uint4*)hin;
    const int lane = threadIdx.x & 63;
    const int wid  = threadIdx.x >> 6;
    const int n15  = lane & 15, quad = lane >> 4;
    const int g = lane >> 3;     // agg: node slot 0..7
    const int q = lane & 7;      // agg: 16B chunk 0..7

    short8 w1f[8], w2f[8];
    const short8* Wp8 = (const short8*)Wp;
#pragma unroll
    for (int f = 0; f < 8; ++f) {
        w1f[f] = Wp8[f * 64 + lane];
        w2f[f] = Wp8[(8 + f) * 64 + lane];
    }
    f32x4 sc[4], sh[4];
#pragma unroll
    for (int mt = 0; mt < 4; ++mt) {
        const int j0 = mt * 16 + quad * 4;
#pragma unroll
        for (int r = 0; r < 4; ++r) {
            float s = gamma[j0 + r] * rsqrtf(rvar[j0 + r] + 1e-5f);
            sc[mt][r] = s;
            sh[mt][r] = (b1[j0 + r] - rmean[j0 + r]) * s + beta[j0 + r];
        }
    }
    float bb2[4];
#pragma unroll
    for (int tc = 0; tc < 4; ++tc) bb2[tc] = b2[tc * 16 + n15];

    const int wave = blockIdx.x * 4 + wid;
    const int nwaves = gridDim.x * 4;
    for (int tile = wave; tile < ntiles; tile += nwaves) {
        const int nb = tile * 16;
        // ---- agg phase: 2 passes of 8 nodes ----
#pragma unroll
        for (int p = 0; p < 2; ++p) {
            const int i = nb + p * 8 + g;
            const int rp0 = row_ptr[i];
            const int deg = row_ptr[i + 1] - rp0;
            float acc[8];
            {   // self term (eps = 0)
                uint4 v = hb4[(size_t)i * 8 + q];
                acc[0] = __uint_as_float(v.x << 16);
                acc[1] = __uint_as_float(v.x & 0xffff0000u);
                acc[2] = __uint_as_float(v.y << 16);
                acc[3] = __uint_as_float(v.y & 0xffff0000u);
                acc[4] = __uint_as_float(v.z << 16);
                acc[5] = __uint_as_float(v.z & 0xffff0000u);
                acc[6] = __uint_as_float(v.w << 16);
                acc[7] = __uint_as_float(v.w & 0xffff0000u);
            }
            int e = 0;
            for (; e + 8 <= deg; e += 8) {   // 8 gathers in flight per group
                int ix[8];
#pragma unroll
                for (int k = 0; k < 8; ++k) ix[k] = col_idx[rp0 + e + k];
                uint4 v[8];
#pragma unroll
                for (int k = 0; k < 8; ++k) v[k] = hb4[(size_t)ix[k] * 8 + q];
#pragma unroll
                for (int k = 0; k < 8; ++k) add_unpack(acc, v[k]);
            }
            if (e + 4 <= deg) {
                int ix[4];
#pragma unroll
                for (int k = 0; k < 4; ++k) ix[k] = col_idx[rp0 + e + k];
                uint4 v[4];
#pragma unroll
                for (int k = 0; k < 4; ++k) v[k] = hb4[(size_t)ix[k] * 8 + q];
#pragma unroll
                for (int k = 0; k < 4; ++k) add_unpack(acc, v[k]);
                e += 4;
            }
            for (; e < deg; ++e) {
                int ix = col_idx[rp0 + e];
                uint4 v = hb4[(size_t)ix * 8 + q];
                add_unpack(acc, v);
            }
            uint4 o;   // pack 8 fp32 -> 8 bf16 (same quantization the tb path had)
            o.x = f2bf(acc[0]) | (f2bf(acc[1]) << 16);
            o.y = f2bf(acc[2]) | (f2bf(acc[3]) << 16);
            o.z = f2bf(acc[4]) | (f2bf(acc[5]) << 16);
            o.w = f2bf(acc[6]) | (f2bf(acc[7]) << 16);
            *(uint4*)&T[wid][p * 8 + g][q * 8] = o;
        }
        __threadfence_block();   // wave-synchronous LDS: writes drain before reads
        // ---- GEMM1: B-frags of t^T from the T tile ----
        short8 t0 = *(const short8*)&T[wid][n15][quad * 8];        // k = 0..31
        short8 t1 = *(const short8*)&T[wid][n15][32 + quad * 8];   // k = 32..63

        f32x4 c1[4];
#pragma unroll
        for (int mt = 0; mt < 4; ++mt) {
            c1[mt] = (f32x4){0.f, 0.f, 0.f, 0.f};
            c1[mt] = __builtin_amdgcn_mfma_f32_16x16x32_bf16(w1f[mt * 2 + 0], t0, c1[mt], 0, 0, 0);
            c1[mt] = __builtin_amdgcn_mfma_f32_16x16x32_bf16(w1f[mt * 2 + 1], t1, c1[mt], 0, 0, 0);
        }
#pragma unroll
        for (int mt = 0; mt < 4; ++mt) {
            float u0 = fmaxf(c1[mt][0] * sc[mt][0] + sh[mt][0], 0.f);
            float u1 = fmaxf(c1[mt][1] * sc[mt][1] + sh[mt][1], 0.f);
            float u2 = fmaxf(c1[mt][2] * sc[mt][2] + sh[mt][2], 0.f);
            float u3 = fmaxf(c1[mt][3] * sc[mt][3] + sh[mt][3], 0.f);
            uint2 pk;
            pk.x = f2bf(u0) | (f2bf(u1) << 16);
            pk.y = f2bf(u2) | (f2bf(u3) << 16);
            *(uint2*)&U[wid][n15][mt * 16 + quad * 4] = pk;
        }
        __threadfence_block();
        short8 u0 = *(const short8*)&U[wid][n15][quad * 8];
        short8 u1 = *(const short8*)&U[wid][n15][32 + quad * 8];

        f32x4 c2[4];
#pragma unroll
        for (int tc = 0; tc < 4; ++tc) {
            c2[tc] = (f32x4){0.f, 0.f, 0.f, 0.f};
            c2[tc] = __builtin_amdgcn_mfma_f32_16x16x32_bf16(u0, w2f[tc * 2 + 0], c2[tc], 0, 0, 0);
            c2[tc] = __builtin_amdgcn_mfma_f32_16x16x32_bf16(u1, w2f[tc * 2 + 1], c2[tc], 0, 0, 0);
        }
#pragma unroll
        for (int tc = 0; tc < 4; ++tc) {
#pragma unroll
            for (int r = 0; r < 4; ++r) {
                float v = fmaxf(c2[tc][r] + bb2[tc], 0.f);
                hout[(size_t)(nb + quad * 4 + r) * 64 + tc * 16 + n15] = (ushort)f2bf(v);
            }
        }
    }
}

// ---------------- global_add_pool (batch sorted -> run-length + atomics) --------

__global__ void pool_kernel(const ushort* __restrict__ hb, const int* __restrict__ batch,
                            float* __restrict__ pooled, int n) {
    const int lane = threadIdx.x & 63;
    const int wid  = threadIdx.x >> 6;
    const int wave = blockIdx.x * 4 + wid;
    const int nwaves = gridDim.x * 4;
    const int per = (n + nwaves - 1) / nwaves;
    const int a = wave * per;
    const int b = min(a + per, n);
    if (a >= b) return;
    int cur = batch[a];
    float sum = 0.0f;
    for (int i = a; i < b; ++i) {
        int g = batch[i];
        if (g != cur) {
            atomicAdd(&pooled[cur * DIM + lane], sum);
            sum = 0.0f;
            cur = g;
        }
        sum += __uint_as_float(((uint)hb[(size_t)i * DIM + lane]) << 16);
    }
    atomicAdd(&pooled[cur * DIM + lane], sum);
}

// ---------------- head: relu(pooled@lin1+b1) @ lin2 + b2 ----------------

__global__ void head_kernel(const float* __restrict__ pooled,
                            const float* __restrict__ w1, const float* __restrict__ b1,
                            const float* __restrict__ w2, const float* __restrict__ b2,
                            float* __restrict__ out) {
    const int g = blockIdx.x;
    const int lane = threadIdx.x;  // 64 threads = 1 wave
    __shared__ float pl[DIM];
    __shared__ float y1l[DIM];
    pl[lane] = pooled[g * DIM + lane];
    __syncthreads();
    float y = b1[lane];
#pragma unroll
    for (int d = 0; d < DIM; ++d) y += pl[d] * w1[d * DIM + lane];
    y1l[lane] = fmaxf(y, 0.0f);
    __syncthreads();
    if (lane < OUT_DIM) {
        float y2 = b2[lane];
#pragma unroll
        for (int d = 0; d < DIM; ++d) y2 += y1l[d] * w2[d * OUT_DIM + lane];
        out[g * OUT_DIM + lane] = y2;
    }
}

// ---------------- launch ----------------

extern "C" void kernel_launch(void* const* d_in, const int* in_sizes, int n_in,
                              void* d_out, int out_size, void* d_ws, size_t ws_size,
                              hipStream_t stream) {
    const float* x     = (const float*)d_in[0];
    const int*   eidx  = (const int*)  d_in[1];   // [2, N_EDGES]: src row then dst row
    const int*   batch = (const int*)  d_in[2];
    const float* W1    = (const float*)d_in[3];
    const float* b1    = (const float*)d_in[4];
    const float* gamma = (const float*)d_in[5];
    const float* beta  = (const float*)d_in[6];
    const float* rmean = (const float*)d_in[7];
    const float* rvar  = (const float*)d_in[8];
    const float* W2    = (const float*)d_in[9];
    const float* b2    = (const float*)d_in[10];
    const float* l1w   = (const float*)d_in[11];
    const float* l1b   = (const float*)d_in[12];
    const float* l2w   = (const float*)d_in[13];
    const float* l2b   = (const float*)d_in[14];
    float* out = (float*)d_out;

    // workspace layout (int-element offsets; 16B alignment preserved)
    const size_t CS = (size_t)SUB * N_RANGES * RANGE_SIZE;   // 1,835,008
    const size_t BS = (size_t)SUB * NODE_PAD;                // 1,835,008
    int* counts224  = (int*)d_ws;                 // 3584
    int* regionOff  = counts224 + 3584;           // 3584
    int* rangeStart = regionOff + 3584;           // 8 (+pad to 64)
    int* blockSums  = rangeStart + 64;            // 256
    int* blockOffs  = blockSums + 256;            // 256
    int* row_ptr    = blockOffs + 256;            // 100352
    int* countsS    = row_ptr + 100352;           // CS
    int* baseS      = countsS + CS;               // BS
    uint2* epart    = (uint2*)(baseS + BS);       // 1.6M uint2 (12.8MB)
    int* col_idx    = (int*)(epart + N_EDGES);    // 1.6M
    uint4* Wp       = (uint4*)(col_idx + 1600000);// 5120 uint4 = 80KB
    ushort* hbA     = (ushort*)(Wp + 5120);       // 100000*64 bf16 (12.8MB)
    ushort* hbB     = hbA + (size_t)N_NODES * DIM;// 100000*64 bf16 (12.8MB)
    float* pooled   = (float*)(hbB + (size_t)N_NODES * DIM);  // 128*64 fp32

    const int* srcp = eidx;
    const int* dstp = eidx + N_EDGES;

    hipMemsetAsync(pooled, 0, N_GRAPHS * DIM * sizeof(float), stream);

    cvt_kernel<<<(N_NODES * DIM / 4 + 255) / 256, 256, 0, stream>>>(x, hbA, N_NODES * DIM / 4);
    repack_kernel<<<1, 640, 0, stream>>>(W1, W2, Wp);
    count224_kernel<<<P_CHUNKS, 256, 0, stream>>>(dstp, counts224);
    scan224_kernel<<<1, 1024, 0, stream>>>(counts224, regionOff, rangeStart);
    partition_kernel<<<P_CHUNKS, 256, 0, stream>>>(srcp, dstp, regionOff, epart);
    histoR_kernel<<<SUB * 8, 1024, 0, stream>>>(epart, rangeStart, countsS);
    scanA_kernel<<<SCAN_NB, 256, 0, stream>>>(countsS, blockSums, N_NODES);
    scanB_kernel<<<1, 256, 0, stream>>>(blockSums, blockOffs, row_ptr);
    scanC_kernel<<<SCAN_NB, 256, 0, stream>>>(countsS, blockOffs, row_ptr, baseS, N_NODES);
    fillR_kernel<<<SUB * 8, 1024, 0, stream>>>(epart, rangeStart, baseS, col_idx);

    const int ntiles = N_NODES / 16;              // 6250 exact
    const int fused_blocks = (ntiles + 3) / 4;    // one tile per wave (1563 blocks)
    // ping-pong: L1 A->B, L2 B->A, L3 A->B, L4 B->A, L5 A->B
    ushort* hin  = hbA;
    ushort* hout = hbB;
    for (int l = 0; l < 5; ++l) {
        gin_fused_kernel<<<fused_blocks, 256, 0, stream>>>(
            hin, hout, row_ptr, col_idx, Wp + (size_t)l * 2 * 8 * 64,
            b1 + (size_t)l * DIM, gamma + (size_t)l * DIM, beta + (size_t)l * DIM,
            rmean + (size_t)l * DIM, rvar + (size_t)l * DIM, b2 + (size_t)l * DIM, ntiles);
        ushort* tmp = hin; hin = hout; hout = tmp;
    }
    pool_kernel<<<2048, 256, 0, stream>>>(hin, batch, pooled, N_NODES);  // hin = last output
    head_kernel<<<N_GRAPHS, 64, 0, stream>>>(pooled, l1w, l1b, l2w, l2b, out);
}

// Round 17
// 412.229 us; speedup vs baseline: 1.1284x; 1.1284x over previous
//
#include <hip/hip_runtime.h>

#define N_NODES  100000
#define N_EDGES  1600000
#define DIM      64
#define N_GRAPHS 128
#define OUT_DIM  10
#define SCAN_NB    196
#define SCAN_CHUNK 512      // 196*512 = 100352 >= N_NODES
#define RANGE_BITS 14
#define RANGE_SIZE 16384    // nodes per dst-range
#define N_RANGES   7        // 7*16384 = 114688 >= N_NODES
#define NODE_PAD   (N_RANGES * RANGE_SIZE) // 114688
#define P_CHUNKS   512
#define P_EDGES    (N_EDGES / P_CHUNKS)    // 3125
#define SUB        16       // subchunks per range for histoR/fillR

typedef unsigned int uint;
typedef unsigned short ushort;
typedef __attribute__((ext_vector_type(8))) short short8;   // 8 bf16 = 4 VGPRs
typedef __attribute__((ext_vector_type(4))) float f32x4;

__device__ __forceinline__ uint f2bf(float x) {   // fp32 -> bf16 bits (RNE)
    uint b = __float_as_uint(x);
    b += 0x7fffu + ((b >> 16) & 1u);
    return b >> 16;
}

// ================= CSR build: range-partition first, then per-range CSR =========

__global__ void count224_kernel(const int* __restrict__ dst, int* __restrict__ counts224) {
    __shared__ int cnt[8];
    const int c = blockIdx.x, tid = threadIdx.x;
    if (tid < 8) cnt[tid] = 0;
    __syncthreads();
    int c0 = 0, c1 = 0, c2 = 0, c3 = 0, c4 = 0, c5 = 0, c6 = 0;
    const int beg = c * P_EDGES, end = beg + P_EDGES;
    for (int i = beg + tid; i < end; i += 256) {
        int r = dst[i] >> RANGE_BITS;
        c0 += (r == 0); c1 += (r == 1); c2 += (r == 2); c3 += (r == 3);
        c4 += (r == 4); c5 += (r == 5); c6 += (r == 6);
    }
    atomicAdd(&cnt[0], c0); atomicAdd(&cnt[1], c1); atomicAdd(&cnt[2], c2);
    atomicAdd(&cnt[3], c3); atomicAdd(&cnt[4], c4); atomicAdd(&cnt[5], c5);
    atomicAdd(&cnt[6], c6);
    __syncthreads();
    if (tid < N_RANGES) counts224[tid * P_CHUNKS + c] = cnt[tid];   // r-major
}

__global__ void scan224_kernel(const int* __restrict__ counts224, int* __restrict__ regionOff,
                               int* __restrict__ rangeStart) {
    __shared__ int sc[1024];
    const int t = threadIdx.x;
    const int NE = N_RANGES * P_CHUNKS;   // 3584 = 896*4
    int v[4];
    int s = 0;
#pragma unroll
    for (int k = 0; k < 4; ++k) {
        const int idx = t * 4 + k;
        v[k] = (idx < NE) ? counts224[idx] : 0;
        s += v[k];
    }
    sc[t] = s;
    __syncthreads();
    for (int off = 1; off < 1024; off <<= 1) {
        int u = (t >= off) ? sc[t - off] : 0;
        __syncthreads();
        sc[t] += u;
        __syncthreads();
    }
    int base = sc[t] - s;   // exclusive prefix for idx = t*4
#pragma unroll
    for (int k = 0; k < 4; ++k) {
        const int idx = t * 4 + k;
        if (idx < NE) {
            regionOff[idx] = base;
            if ((idx & (P_CHUNKS - 1)) == 0) rangeStart[idx >> 9] = base;
            base += v[k];
        }
    }
    if (t == 1023) rangeStart[N_RANGES] = sc[1023];   // total = N_EDGES
}

__global__ __launch_bounds__(256) void partition_kernel(
    const int* __restrict__ src, const int* __restrict__ dst,
    const int* __restrict__ regionOff, uint2* __restrict__ epart) {
    __shared__ int pos[8];
    const int c = blockIdx.x, tid = threadIdx.x;
    if (tid < N_RANGES) pos[tid] = regionOff[tid * P_CHUNKS + c];
    __syncthreads();
    const int beg = c * P_EDGES, end = beg + P_EDGES;
    for (int i = beg + tid; i < end; i += 256) {
        int d = dst[i], s = src[i];
        int p = atomicAdd(&pos[d >> RANGE_BITS], 1);
        epart[p] = make_uint2((uint)s, (uint)d);
    }
}

__global__ __launch_bounds__(1024) void histoR_kernel(const uint2* __restrict__ epart,
                                                      const int* __restrict__ rangeStart,
                                                      int* __restrict__ countsS) {
    __shared__ int h[RANGE_SIZE];
    const int r = blockIdx.x & 7;           // XCD = r
    if (r >= N_RANGES) return;
    const int s = blockIdx.x >> 3;
    const int tid = threadIdx.x;
    for (int j = tid; j < RANGE_SIZE; j += 1024) h[j] = 0;
    __syncthreads();
    const int e0 = rangeStart[r], e1 = rangeStart[r + 1];
    const int len = e1 - e0;
    const int a = e0 + (int)((long long)len * s / SUB);
    const int b = e0 + (int)((long long)len * (s + 1) / SUB);
    for (int i = a + tid; i < b; i += 1024)
        atomicAdd(&h[epart[i].y & (RANGE_SIZE - 1)], 1);
    __syncthreads();
    int* outp = countsS + (s * N_RANGES + r) * RANGE_SIZE;
    for (int j = tid; j < RANGE_SIZE; j += 1024) outp[j] = h[j];
}

__global__ void scanA_kernel(const int* __restrict__ countsS, int* __restrict__ blockSums, int n) {
    __shared__ int red[256];
    const int b = blockIdx.x, t = threadIdx.x;
    int sum = 0;
#pragma unroll
    for (int k = 0; k < 2; ++k) {
        const int node = b * SCAN_CHUNK + t * 2 + k;
        if (node < n) {
            const int r = node >> RANGE_BITS, jj = node & (RANGE_SIZE - 1);
            for (int s = 0; s < SUB; ++s)
                sum += countsS[(s * N_RANGES + r) * RANGE_SIZE + jj];
        }
    }
    red[t] = sum;
    __syncthreads();
    for (int off = 128; off > 0; off >>= 1) {
        if (t < off) red[t] += red[t + off];
        __syncthreads();
    }
    if (t == 0) blockSums[b] = red[0];
}

__global__ void scanB_kernel(const int* __restrict__ blockSums, int* __restrict__ blockOffs,
                             int* __restrict__ row_ptr) {
    __shared__ int sc[256];
    const int t = threadIdx.x;
    const int v = (t < SCAN_NB) ? blockSums[t] : 0;
    sc[t] = v;
    __syncthreads();
    for (int off = 1; off < 256; off <<= 1) {
        int u = (t >= off) ? sc[t - off] : 0;
        __syncthreads();
        sc[t] += u;
        __syncthreads();
    }
    if (t < SCAN_NB) blockOffs[t] = sc[t] - v;   // exclusive block offset
    if (t == 255) row_ptr[N_NODES] = sc[255];    // total == N_EDGES
}

__global__ void scanC_kernel(const int* __restrict__ countsS, const int* __restrict__ blockOffs,
                             int* __restrict__ row_ptr, int* __restrict__ baseS, int n) {
    __shared__ int sc[256];
    const int b = blockIdx.x, t = threadIdx.x;
    const int node0 = b * SCAN_CHUNK + t * 2;
    int cnt0[SUB], cnt1[SUB];
    int tot0 = 0, tot1 = 0;
    if (node0 < n) {
        const int r = node0 >> RANGE_BITS, jj = node0 & (RANGE_SIZE - 1);
        for (int s = 0; s < SUB; ++s) {
            cnt0[s] = countsS[(s * N_RANGES + r) * RANGE_SIZE + jj];
            tot0 += cnt0[s];
        }
    }
    if (node0 + 1 < n) {
        const int r = (node0 + 1) >> RANGE_BITS, jj = (node0 + 1) & (RANGE_SIZE - 1);
        for (int s = 0; s < SUB; ++s) {
            cnt1[s] = countsS[(s * N_RANGES + r) * RANGE_SIZE + jj];
            tot1 += cnt1[s];
        }
    }
    const int ssum = tot0 + tot1;
    sc[t] = ssum;
    __syncthreads();
    for (int off = 1; off < 256; off <<= 1) {
        int u = (t >= off) ? sc[t - off] : 0;
        __syncthreads();
        sc[t] += u;
        __syncthreads();
    }
    const int pre = blockOffs[b] + sc[t] - ssum;
    if (node0 < n) {
        row_ptr[node0] = pre;
        int run = pre;
        for (int s = 0; s < SUB; ++s) { baseS[s * NODE_PAD + node0] = run; run += cnt0[s]; }
    }
    if (node0 + 1 < n) {
        const int pre1 = pre + tot0;
        row_ptr[node0 + 1] = pre1;
        int run = pre1;
        for (int s = 0; s < SUB; ++s) { baseS[s * NODE_PAD + node0 + 1] = run; run += cnt1[s]; }
    }
}

__global__ __launch_bounds__(1024) void fillR_kernel(const uint2* __restrict__ epart,
                                                     const int* __restrict__ rangeStart,
                                                     const int* __restrict__ baseS,
                                                     int* __restrict__ col_idx) {
    __shared__ int slots[RANGE_SIZE];
    const int r = blockIdx.x & 7;           // XCD = r
    if (r >= N_RANGES) return;
    const int s = blockIdx.x >> 3;
    const int tid = threadIdx.x;
    const int* bp = baseS + s * NODE_PAD + r * RANGE_SIZE;
    for (int j = tid; j < RANGE_SIZE; j += 1024) slots[j] = bp[j];
    __syncthreads();
    const int e0 = rangeStart[r], e1 = rangeStart[r + 1];
    const int len = e1 - e0;
    const int a = e0 + (int)((long long)len * s / SUB);
    const int b = e0 + (int)((long long)len * (s + 1) / SUB);
    for (int i = a + tid; i < b; i += 1024) {
        uint2 e = epart[i];
        int pos = atomicAdd(&slots[e.y & (RANGE_SIZE - 1)], 1);
        col_idx[pos] = (int)e.x;
    }
}

// ---------------- x (fp32) -> bf16 rows ----------------

__global__ void cvt_kernel(const float* __restrict__ x, ushort* __restrict__ xb, int n4) {
    int idx = blockIdx.x * blockDim.x + threadIdx.x;
    if (idx >= n4) return;
    float4 v = ((const float4*)x)[idx];
    uint2 o;
    o.x = f2bf(v.x) | (f2bf(v.y) << 16);
    o.y = f2bf(v.z) | (f2bf(v.w) << 16);
    ((uint2*)xb)[idx] = o;
}

// ---------------- Weight repack: MFMA fragment layouts, once per launch ----------

__global__ void repack_kernel(const float* __restrict__ W1, const float* __restrict__ W2,
                              uint4* __restrict__ Wp) {
    const int wave = (blockIdx.x * blockDim.x + threadIdx.x) >> 6;
    if (wave >= 10) return;
    const int layer = wave >> 1;
    const float* W = (wave & 1) ? (W2 + layer * 4096) : (W1 + layer * 4096);
    const int lane = threadIdx.x & 63;
    const int n15 = lane & 15, quad = lane >> 4;
#pragma unroll
    for (int f = 0; f < 8; ++f) {
        const int outer = f >> 1, h = f & 1;
        uint p[4];
#pragma unroll
        for (int pj = 0; pj < 4; ++pj) {
            const int k0 = h * 32 + quad * 8 + 2 * pj;
            uint lo = f2bf(W[k0 * 64 + outer * 16 + n15]);
            uint hi = f2bf(W[(k0 + 1) * 64 + outer * 16 + n15]);
            p[pj] = lo | (hi << 16);
        }
        Wp[(wave * 8 + f) * 64 + lane] = make_uint4(p[0], p[1], p[2], p[3]);
    }
}

// ---------------- Aggregation: tb[i] = hb[i] + sum_{j in N(i)} hb[j] -> bf16 ------
// GROUP-PER-NODE: 8 lanes/node, 8 nodes/wave; unroll 8. No min-waves bound
// (R11: (256,8) squeezed VGPR to 32 -> scratch spill). Split from MLP: fused
// variants (R15/R16) were 20-50us slower — independent small agg waves get
// better machine-wide gather concurrency than fused mega-waves.

__device__ __forceinline__ void add_unpack(float acc[8], uint4 v) {
    acc[0] += __uint_as_float(v.x << 16);
    acc[1] += __uint_as_float(v.x & 0xffff0000u);
    acc[2] += __uint_as_float(v.y << 16);
    acc[3] += __uint_as_float(v.y & 0xffff0000u);
    acc[4] += __uint_as_float(v.z << 16);
    acc[5] += __uint_as_float(v.z & 0xffff0000u);
    acc[6] += __uint_as_float(v.w << 16);
    acc[7] += __uint_as_float(v.w & 0xffff0000u);
}

__global__ __launch_bounds__(256) void agg_kernel(
    const ushort* __restrict__ hb, ushort* __restrict__ tb,
    const int* __restrict__ row_ptr, const int* __restrict__ col_idx, int n)
{
    const uint4* __restrict__ hb4 = (const uint4*)hb;   // row = 8 uint4
    const int lane = threadIdx.x & 63;
    const int g = lane >> 3;     // node slot 0..7 within wave
    const int q = lane & 7;      // 16B chunk 0..7 within row
    const int wave = (blockIdx.x * blockDim.x + threadIdx.x) >> 6;
    const int i = wave * 8 + g;
    if (i >= n) return;
    const int rp0 = row_ptr[i];
    const int deg = row_ptr[i + 1] - rp0;

    float acc[8];
    {   // self term (eps = 0) — safe in init: no cross-lane reduction follows
        uint4 v = hb4[(size_t)i * 8 + q];
        acc[0] = __uint_as_float(v.x << 16);
        acc[1] = __uint_as_float(v.x & 0xffff0000u);
        acc[2] = __uint_as_float(v.y << 16);
        acc[3] = __uint_as_float(v.y & 0xffff0000u);
        acc[4] = __uint_as_float(v.z << 16);
        acc[5] = __uint_as_float(v.z & 0xffff0000u);
        acc[6] = __uint_as_float(v.w << 16);
        acc[7] = __uint_as_float(v.w & 0xffff0000u);
    }

    int e = 0;
    for (; e + 8 <= deg; e += 8) {   // 8 gathers in flight per group
        int ix[8];
#pragma unroll
        for (int k = 0; k < 8; ++k) ix[k] = col_idx[rp0 + e + k];
        uint4 v[8];
#pragma unroll
        for (int k = 0; k < 8; ++k) v[k] = hb4[(size_t)ix[k] * 8 + q];
#pragma unroll
        for (int k = 0; k < 8; ++k) add_unpack(acc, v[k]);
    }
    if (e + 4 <= deg) {
        int ix[4];
#pragma unroll
        for (int k = 0; k < 4; ++k) ix[k] = col_idx[rp0 + e + k];
        uint4 v[4];
#pragma unroll
        for (int k = 0; k < 4; ++k) v[k] = hb4[(size_t)ix[k] * 8 + q];
#pragma unroll
        for (int k = 0; k < 4; ++k) add_unpack(acc, v[k]);
        e += 4;
    }
    for (; e < deg; ++e) {
        int ix = col_idx[rp0 + e];
        uint4 v = hb4[(size_t)ix * 8 + q];
        add_unpack(acc, v);
    }

    uint4 o;   // pack 8 fp32 -> 8 bf16 (dims q*8 .. q*8+7)
    o.x = f2bf(acc[0]) | (f2bf(acc[1]) << 16);
    o.y = f2bf(acc[2]) | (f2bf(acc[3]) << 16);
    o.z = f2bf(acc[4]) | (f2bf(acc[5]) << 16);
    o.w = f2bf(acc[6]) | (f2bf(acc[7]) << 16);
    ((uint4*)tb)[(size_t)i * 8 + q] = o;
}

// ---------------- MLP via MFMA (R7 structure) ----------------

__global__ __launch_bounds__(256) void mlp_kernel(
    const ushort* __restrict__ tb, ushort* __restrict__ hb,
    const uint4* __restrict__ Wp,   // layer frags: [0..7]=W1^T, [8..15]=W2
    const float* __restrict__ b1, const float* __restrict__ gamma,
    const float* __restrict__ beta, const float* __restrict__ rmean,
    const float* __restrict__ rvar, const float* __restrict__ b2, int ntiles)
{
    __shared__ __align__(16) ushort U[4][16][72];   // stride 72 breaks pow-2 banks
    const int lane = threadIdx.x & 63;
    const int wid  = threadIdx.x >> 6;
    const int n15  = lane & 15, quad = lane >> 4;

    short8 w1f[8], w2f[8];
    const short8* Wp8 = (const short8*)Wp;
#pragma unroll
    for (int f = 0; f < 8; ++f) {
        w1f[f] = Wp8[f * 64 + lane];
        w2f[f] = Wp8[(8 + f) * 64 + lane];
    }
    f32x4 sc[4], sh[4];
#pragma unroll
    for (int mt = 0; mt < 4; ++mt) {
        const int j0 = mt * 16 + quad * 4;
#pragma unroll
        for (int r = 0; r < 4; ++r) {
            float s = gamma[j0 + r] * rsqrtf(rvar[j0 + r] + 1e-5f);
            sc[mt][r] = s;
            sh[mt][r] = (b1[j0 + r] - rmean[j0 + r]) * s + beta[j0 + r];
        }
    }
    float bb2[4];
#pragma unroll
    for (int tc = 0; tc < 4; ++tc) bb2[tc] = b2[tc * 16 + n15];

    const int wave = blockIdx.x * 4 + wid;
    const int nwaves = gridDim.x * 4;
    for (int tile = wave; tile < ntiles; tile += nwaves) {
        const int nb = tile * 16;
        const short8* trow = (const short8*)(tb + (size_t)(nb + n15) * 64);
        short8 t0 = trow[quad];        // k = 0..31 half
        short8 t1 = trow[4 + quad];    // k = 32..63 half

        f32x4 c1[4];
#pragma unroll
        for (int mt = 0; mt < 4; ++mt) {
            c1[mt] = (f32x4){0.f, 0.f, 0.f, 0.f};
            c1[mt] = __builtin_amdgcn_mfma_f32_16x16x32_bf16(w1f[mt * 2 + 0], t0, c1[mt], 0, 0, 0);
            c1[mt] = __builtin_amdgcn_mfma_f32_16x16x32_bf16(w1f[mt * 2 + 1], t1, c1[mt], 0, 0, 0);
        }
#pragma unroll
        for (int mt = 0; mt < 4; ++mt) {
            float u0 = fmaxf(c1[mt][0] * sc[mt][0] + sh[mt][0], 0.f);
            float u1 = fmaxf(c1[mt][1] * sc[mt][1] + sh[mt][1], 0.f);
            float u2 = fmaxf(c1[mt][2] * sc[mt][2] + sh[mt][2], 0.f);
            float u3 = fmaxf(c1[mt][3] * sc[mt][3] + sh[mt][3], 0.f);
            uint2 pk;
            pk.x = f2bf(u0) | (f2bf(u1) << 16);
            pk.y = f2bf(u2) | (f2bf(u3) << 16);
            *(uint2*)&U[wid][n15][mt * 16 + quad * 4] = pk;
        }
        __threadfence_block();
        short8 u0 = *(const short8*)&U[wid][n15][quad * 8];
        short8 u1 = *(const short8*)&U[wid][n15][32 + quad * 8];

        f32x4 c2[4];
#pragma unroll
        for (int tc = 0; tc < 4; ++tc) {
            c2[tc] = (f32x4){0.f, 0.f, 0.f, 0.f};
            c2[tc] = __builtin_amdgcn_mfma_f32_16x16x32_bf16(u0, w2f[tc * 2 + 0], c2[tc], 0, 0, 0);
            c2[tc] = __builtin_amdgcn_mfma_f32_16x16x32_bf16(u1, w2f[tc * 2 + 1], c2[tc], 0, 0, 0);
        }
#pragma unroll
        for (int tc = 0; tc < 4; ++tc) {
#pragma unroll
            for (int r = 0; r < 4; ++r) {
                float v = fmaxf(c2[tc][r] + bb2[tc], 0.f);
                hb[(size_t)(nb + quad * 4 + r) * 64 + tc * 16 + n15] = (ushort)f2bf(v);
            }
        }
    }
}

// ---------------- global_add_pool (batch sorted -> run-length + atomics) --------

__global__ void pool_kernel(const ushort* __restrict__ hb, const int* __restrict__ batch,
                            float* __restrict__ pooled, int n) {
    const int lane = threadIdx.x & 63;
    const int wid  = threadIdx.x >> 6;
    const int wave = blockIdx.x * 4 + wid;
    const int nwaves = gridDim.x * 4;
    const int per = (n + nwaves - 1) / nwaves;
    const int a = wave * per;
    const int b = min(a + per, n);
    if (a >= b) return;
    int cur = batch[a];
    float sum = 0.0f;
    for (int i = a; i < b; ++i) {
        int g = batch[i];
        if (g != cur) {
            atomicAdd(&pooled[cur * DIM + lane], sum);
            sum = 0.0f;
            cur = g;
        }
        sum += __uint_as_float(((uint)hb[(size_t)i * DIM + lane]) << 16);
    }
    atomicAdd(&pooled[cur * DIM + lane], sum);
}

// ---------------- head: relu(pooled@lin1+b1) @ lin2 + b2 ----------------

__global__ void head_kernel(const float* __restrict__ pooled,
                            const float* __restrict__ w1, const float* __restrict__ b1,
                            const float* __restrict__ w2, const float* __restrict__ b2,
                            float* __restrict__ out) {
    const int g = blockIdx.x;
    const int lane = threadIdx.x;  // 64 threads = 1 wave
    __shared__ float pl[DIM];
    __shared__ float y1l[DIM];
    pl[lane] = pooled[g * DIM + lane];
    __syncthreads();
    float y = b1[lane];
#pragma unroll
    for (int d = 0; d < DIM; ++d) y += pl[d] * w1[d * DIM + lane];
    y1l[lane] = fmaxf(y, 0.0f);
    __syncthreads();
    if (lane < OUT_DIM) {
        float y2 = b2[lane];
#pragma unroll
        for (int d = 0; d < DIM; ++d) y2 += y1l[d] * w2[d * OUT_DIM + lane];
        out[g * OUT_DIM + lane] = y2;
    }
}

// ---------------- launch ----------------

extern "C" void kernel_launch(void* const* d_in, const int* in_sizes, int n_in,
                              void* d_out, int out_size, void* d_ws, size_t ws_size,
                              hipStream_t stream) {
    const float* x     = (const float*)d_in[0];
    const int*   eidx  = (const int*)  d_in[1];   // [2, N_EDGES]: src row then dst row
    const int*   batch = (const int*)  d_in[2];
    const float* W1    = (const float*)d_in[3];
    const float* b1    = (const float*)d_in[4];
    const float* gamma = (const float*)d_in[5];
    const float* beta  = (const float*)d_in[6];
    const float* rmean = (const float*)d_in[7];
    const float* rvar  = (const float*)d_in[8];
    const float* W2    = (const float*)d_in[9];
    const float* b2    = (const float*)d_in[10];
    const float* l1w   = (const float*)d_in[11];
    const float* l1b   = (const float*)d_in[12];
    const float* l2w   = (const float*)d_in[13];
    const float* l2b   = (const float*)d_in[14];
    float* out = (float*)d_out;

    // workspace layout (int-element offsets; 16B alignment preserved)
    const size_t CS = (size_t)SUB * N_RANGES * RANGE_SIZE;   // 1,835,008
    const size_t BS = (size_t)SUB * NODE_PAD;                // 1,835,008
    int* counts224  = (int*)d_ws;                 // 3584
    int* regionOff  = counts224 + 3584;           // 3584
    int* rangeStart = regionOff + 3584;           // 8 (+pad to 64)
    int* blockSums  = rangeStart + 64;            // 256
    int* blockOffs  = blockSums + 256;            // 256
    int* row_ptr    = blockOffs + 256;            // 100352
    int* countsS    = row_ptr + 100352;           // CS
    int* baseS      = countsS + CS;               // BS
    uint2* epart    = (uint2*)(baseS + BS);       // 1.6M uint2 (12.8MB)
    int* col_idx    = (int*)(epart + N_EDGES);    // 1.6M
    uint4* Wp       = (uint4*)(col_idx + 1600000);// 5120 uint4 = 80KB
    ushort* tb      = (ushort*)(Wp + 5120);       // 100000*64 bf16 (12.8MB)
    ushort* hb      = tb + (size_t)N_NODES * DIM; // 100000*64 bf16 (12.8MB)
    float* pooled   = (float*)(hb + (size_t)N_NODES * DIM);  // 128*64 fp32

    const int* srcp = eidx;
    const int* dstp = eidx + N_EDGES;

    hipMemsetAsync(pooled, 0, N_GRAPHS * DIM * sizeof(float), stream);

    cvt_kernel<<<(N_NODES * DIM / 4 + 255) / 256, 256, 0, stream>>>(x, hb, N_NODES * DIM / 4);
    repack_kernel<<<1, 640, 0, stream>>>(W1, W2, Wp);
    count224_kernel<<<P_CHUNKS, 256, 0, stream>>>(dstp, counts224);
    scan224_kernel<<<1, 1024, 0, stream>>>(counts224, regionOff, rangeStart);
    partition_kernel<<<P_CHUNKS, 256, 0, stream>>>(srcp, dstp, regionOff, epart);
    histoR_kernel<<<SUB * 8, 1024, 0, stream>>>(epart, rangeStart, countsS);
    scanA_kernel<<<SCAN_NB, 256, 0, stream>>>(countsS, blockSums, N_NODES);
    scanB_kernel<<<1, 256, 0, stream>>>(blockSums, blockOffs, row_ptr);
    scanC_kernel<<<SCAN_NB, 256, 0, stream>>>(countsS, blockOffs, row_ptr, baseS, N_NODES);
    fillR_kernel<<<SUB * 8, 1024, 0, stream>>>(epart, rangeStart, baseS, col_idx);

    const int agg_blocks = ((N_NODES + 7) / 8 * 64 + 255) / 256;  // 8 nodes per wave
    const int ntiles = N_NODES / 16;                               // 6250 exact

    for (int l = 0; l < 5; ++l) {
        agg_kernel<<<agg_blocks, 256, 0, stream>>>(hb, tb, row_ptr, col_idx, N_NODES);
        mlp_kernel<<<512, 256, 0, stream>>>(
            tb, hb, Wp + (size_t)l * 2 * 8 * 64,
            b1 + (size_t)l * DIM, gamma + (size_t)l * DIM, beta + (size_t)l * DIM,
            rmean + (size_t)l * DIM, rvar + (size_t)l * DIM, b2 + (size_t)l * DIM, ntiles);
    }
    pool_kernel<<<2048, 256, 0, stream>>>(hb, batch, pooled, N_NODES);
    head_kernel<<<N_GRAPHS, 64, 0, stream>>>(pooled, l1w, l1b, l2w, l2b, out);
}